// Round 1
// baseline (6509.020 us; speedup 1.0000x reference)
//
#include <hip/hip_runtime.h>
#include <math.h>

constexpr int cB  = 262144;
constexpr int cCD = 2;
constexpr int cE  = 64;
constexpr int cH  = 128;
constexpr int cK  = 32;
constexpr int cL  = 6;
constexpr int cNB = 2;
constexpr int cP  = 95;      // 3K-1
constexpr float cTB = 6.0f;
constexpr float cMB = 0.001f;   // MIN_BIN
constexpr float cMD = 0.001f;   // MIN_DERIV
constexpr int M = 32;           // samples per workgroup
constexpr int NTHREADS = 256;

__device__ __forceinline__ float eluf(float x) {
  return x > 0.0f ? x : __expf(x) - 1.0f;
}
__device__ __forceinline__ float sigmf(float x) {
  return 1.0f / (1.0f + __expf(-x));
}
__device__ __forceinline__ float softplusf_(float x) {
  return x > 20.0f ? x : log1pf(__expf(x));
}

// 4x4 outer-product FMA on float4 (w -> f dim, a -> m dim)
#define FMA16(ACC, WV, AV)                                                      \
  ACC[0][0] += WV.x * AV.x; ACC[0][1] += WV.x * AV.y;                           \
  ACC[0][2] += WV.x * AV.z; ACC[0][3] += WV.x * AV.w;                           \
  ACC[1][0] += WV.y * AV.x; ACC[1][1] += WV.y * AV.y;                           \
  ACC[1][2] += WV.y * AV.z; ACC[1][3] += WV.y * AV.w;                           \
  ACC[2][0] += WV.z * AV.x; ACC[2][1] += WV.z * AV.y;                           \
  ACC[2][2] += WV.z * AV.z; ACC[2][3] += WV.z * AV.w;                           \
  ACC[3][0] += WV.w * AV.x; ACC[3][1] += WV.w * AV.y;                           \
  ACC[3][2] += WV.w * AV.z; ACC[3][3] += WV.w * AV.w;

__global__ __launch_bounds__(NTHREADS) void nsf_fused(
    const float* __restrict__ gy,   const float* __restrict__ gctx,
    const float* __restrict__ eW1,  const float* __restrict__ eb1,
    const float* __restrict__ eW2,  const float* __restrict__ eb2,
    const float* __restrict__ eW3,  const float* __restrict__ eb3,
    const float* __restrict__ gib,  const float* __restrict__ gcW,
    const float* __restrict__ gcb,  const float* __restrict__ bW1,
    const float* __restrict__ bb1,  const float* __restrict__ bW2,
    const float* __restrict__ bb2,  const float* __restrict__ bWc,
    const float* __restrict__ bbc,  const float* __restrict__ goW,
    const float* __restrict__ gob,  float* __restrict__ gout)
{
  __shared__ float sEmb[cE][M];   // final embedding (elu'd), [e][m]
  __shared__ float sA[cH][M];     // elu(h) during blocks; raw h at layer end
  __shared__ float sT[cH][M];     // elu(t1); aliased as p-buffer [M][97]
  float* sP = &sT[0][0];          // p view: sP[m*97 + q], q < 95

  const int tid = threadIdx.x;
  const int m0 = blockIdx.x * M;
  const int fg = tid >> 3;        // 0..31  -> f block
  const int mg = tid & 7;         // 0..7   -> m block
  const int fbase = fg * 4;
  const int mbase = mg * 4;

  // ------------------- embedding chain -------------------
  {
    const int m = tid & 31;
    const int e0 = tid >> 5;      // 0..7
    const float2 c = *reinterpret_cast<const float2*>(&gctx[(m0 + m) * cCD]);
    #pragma unroll
    for (int j = 0; j < 8; ++j) {
      const int e = e0 + 8 * j;
      sEmb[e][m] = eluf(c.x * eW1[e] + c.y * eW1[cE + e] + eb1[e]);
    }
  }
  __syncthreads();
  {
    const int m = tid & 31;
    const int e0 = tid >> 5;
    float acc[8];
    #pragma unroll
    for (int j = 0; j < 8; ++j) acc[j] = eb2[e0 + 8 * j];
    #pragma unroll 4
    for (int kk = 0; kk < cE; ++kk) {
      const float a = sEmb[kk][m];
      #pragma unroll
      for (int j = 0; j < 8; ++j) acc[j] += a * eW2[kk * cE + e0 + 8 * j];
    }
    #pragma unroll
    for (int j = 0; j < 8; ++j) sA[e0 + 8 * j][m] = eluf(acc[j]);
  }
  __syncthreads();
  {
    const int m = tid & 31;
    const int e0 = tid >> 5;
    float acc[8];
    #pragma unroll
    for (int j = 0; j < 8; ++j) acc[j] = eb3[e0 + 8 * j];
    #pragma unroll 4
    for (int kk = 0; kk < cE; ++kk) {
      const float a = sA[kk][m];
      #pragma unroll
      for (int j = 0; j < 8; ++j) acc[j] += a * eW3[kk * cE + e0 + 8 * j];
    }
    #pragma unroll
    for (int j = 0; j < 8; ++j) sEmb[e0 + 8 * j][m] = eluf(acc[j]);
  }
  __syncthreads();

  // ------------------- flow layers -------------------
  float z = 0.0f, lad = 0.0f;
  if (tid < M) z = gy[m0 + tid];

  float hreg[4][4];   // raw h for this thread's (f, m) tile

  for (int l = 0; l < cL; ++l) {
    // ---- h = init_b + ctx_b + emb @ ctx_W[l] ----
    {
      const float* W = gcW + (size_t)l * cE * cH;
      float acc[4][4];
      #pragma unroll
      for (int i = 0; i < 4; ++i)
        #pragma unroll
        for (int j = 0; j < 4; ++j) acc[i][j] = 0.0f;
      #pragma unroll 8
      for (int kk = 0; kk < cE; ++kk) {
        const float4 wv = *reinterpret_cast<const float4*>(&W[kk * cH + fbase]);
        const float4 av = *reinterpret_cast<const float4*>(&sEmb[kk][mbase]);
        FMA16(acc, wv, av)
      }
      const float4 b0 = *reinterpret_cast<const float4*>(&gib[l * cH + fbase]);
      const float4 b1 = *reinterpret_cast<const float4*>(&gcb[l * cH + fbase]);
      const float bb[4] = {b0.x + b1.x, b0.y + b1.y, b0.z + b1.z, b0.w + b1.w};
      #pragma unroll
      for (int i = 0; i < 4; ++i) {
        float4 st;
        hreg[i][0] = acc[i][0] + bb[i];
        hreg[i][1] = acc[i][1] + bb[i];
        hreg[i][2] = acc[i][2] + bb[i];
        hreg[i][3] = acc[i][3] + bb[i];
        st.x = eluf(hreg[i][0]); st.y = eluf(hreg[i][1]);
        st.z = eluf(hreg[i][2]); st.w = eluf(hreg[i][3]);
        *reinterpret_cast<float4*>(&sA[fbase + i][mbase]) = st;
      }
    }
    __syncthreads();

    // ---- residual blocks ----
    for (int jb = 0; jb < cNB; ++jb) {
      const int wi = l * cNB + jb;
      // t1 = elu( elu(h) @ W1 + b1 )  -> sT
      {
        const float* W = bW1 + (size_t)wi * cH * cH;
        float acc[4][4];
        #pragma unroll
        for (int i = 0; i < 4; ++i)
          #pragma unroll
          for (int j = 0; j < 4; ++j) acc[i][j] = 0.0f;
        #pragma unroll 8
        for (int kk = 0; kk < cH; ++kk) {
          const float4 wv = *reinterpret_cast<const float4*>(&W[kk * cH + fbase]);
          const float4 av = *reinterpret_cast<const float4*>(&sA[kk][mbase]);
          FMA16(acc, wv, av)
        }
        const float4 bv = *reinterpret_cast<const float4*>(&bb1[wi * cH + fbase]);
        const float bb[4] = {bv.x, bv.y, bv.z, bv.w};
        #pragma unroll
        for (int i = 0; i < 4; ++i) {
          float4 st;
          st.x = eluf(acc[i][0] + bb[i]); st.y = eluf(acc[i][1] + bb[i]);
          st.z = eluf(acc[i][2] + bb[i]); st.w = eluf(acc[i][3] + bb[i]);
          *reinterpret_cast<float4*>(&sT[fbase + i][mbase]) = st;
        }
      }
      __syncthreads();
      // t2 = elu(t1) @ W2 + b2 ; gate = sigmoid(emb @ Wc + bc); h += t2*gate
      {
        const float* W2 = bW2 + (size_t)wi * cH * cH;
        const float* Wc = bWc + (size_t)wi * cE * cH;
        float a2[4][4], ag[4][4];
        #pragma unroll
        for (int i = 0; i < 4; ++i)
          #pragma unroll
          for (int j = 0; j < 4; ++j) { a2[i][j] = 0.0f; ag[i][j] = 0.0f; }
        #pragma unroll 8
        for (int kk = 0; kk < cH; ++kk) {
          const float4 wv = *reinterpret_cast<const float4*>(&W2[kk * cH + fbase]);
          const float4 av = *reinterpret_cast<const float4*>(&sT[kk][mbase]);
          FMA16(a2, wv, av)
        }
        #pragma unroll 8
        for (int kk = 0; kk < cE; ++kk) {
          const float4 wv = *reinterpret_cast<const float4*>(&Wc[kk * cH + fbase]);
          const float4 av = *reinterpret_cast<const float4*>(&sEmb[kk][mbase]);
          FMA16(ag, wv, av)
        }
        const float4 b2v = *reinterpret_cast<const float4*>(&bb2[wi * cH + fbase]);
        const float4 bcv = *reinterpret_cast<const float4*>(&bbc[wi * cH + fbase]);
        const float b2a[4] = {b2v.x, b2v.y, b2v.z, b2v.w};
        const float bca[4] = {bcv.x, bcv.y, bcv.z, bcv.w};
        const bool last = (jb == cNB - 1);
        #pragma unroll
        for (int i = 0; i < 4; ++i) {
          float4 st;
          #pragma unroll
          for (int j = 0; j < 4; ++j) {
            const float gate = sigmf(ag[i][j] + bca[i]);
            hreg[i][j] += (a2[i][j] + b2a[i]) * gate;
          }
          st.x = last ? hreg[i][0] : eluf(hreg[i][0]);
          st.y = last ? hreg[i][1] : eluf(hreg[i][1]);
          st.z = last ? hreg[i][2] : eluf(hreg[i][2]);
          st.w = last ? hreg[i][3] : eluf(hreg[i][3]);
          *reinterpret_cast<float4*>(&sA[fbase + i][mbase]) = st;
        }
      }
      __syncthreads();
    }

    // ---- p = h @ out_W[l] + out_b[l]  (sA holds RAW h now) -> sP ----
    {
      const float* Wl = goW + (size_t)l * cH * cP;
      const int qg = tid >> 3;  // 0..31; this thread's q set: {qg, qg+32, qg+64}
      float p0[4] = {0, 0, 0, 0}, p1[4] = {0, 0, 0, 0}, p2[4] = {0, 0, 0, 0};
      #pragma unroll 4
      for (int kk = 0; kk < cH; ++kk) {
        const float4 av = *reinterpret_cast<const float4*>(&sA[kk][mbase]);
        const float w0 = Wl[kk * cP + qg];
        const float w1 = Wl[kk * cP + qg + 32];
        const float w2 = (qg < 31) ? Wl[kk * cP + qg + 64] : 0.0f;
        p0[0] += w0 * av.x; p0[1] += w0 * av.y; p0[2] += w0 * av.z; p0[3] += w0 * av.w;
        p1[0] += w1 * av.x; p1[1] += w1 * av.y; p1[2] += w1 * av.z; p1[3] += w1 * av.w;
        p2[0] += w2 * av.x; p2[1] += w2 * av.y; p2[2] += w2 * av.z; p2[3] += w2 * av.w;
      }
      const float* obl = gob + l * cP;
      const float ob0 = obl[qg];
      const float ob1 = obl[qg + 32];
      const float ob2 = (qg < 31) ? obl[qg + 64] : 0.0f;
      #pragma unroll
      for (int j = 0; j < 4; ++j) {
        const int m = mbase + j;
        sP[m * 97 + qg]      = p0[j] + ob0;
        sP[m * 97 + qg + 32] = p1[j] + ob1;
        if (qg < 31) sP[m * 97 + qg + 64] = p2[j] + ob2;
      }
    }
    __syncthreads();

    // ---- rational-quadratic spline, one thread per sample ----
    if (tid < M) {
      const float invS = 0.08838834764831845f;  // 1/sqrt(128)
      const float* pm = &sP[tid * 97];
      // softmax statistics (on unscaled p; scale applied inside exp arg)
      float mw = pm[0], mh = pm[32];
      #pragma unroll
      for (int i = 1; i < 32; ++i) {
        mw = fmaxf(mw, pm[i]);
        mh = fmaxf(mh, pm[32 + i]);
      }
      float sw = 0.0f, sh = 0.0f;
      #pragma unroll
      for (int i = 0; i < 32; ++i) {
        sw += __expf((pm[i] - mw) * invS);
        sh += __expf((pm[32 + i] - mh) * invS);
      }
      const float cw_scale = (1.0f - cMB * cK) / sw;
      const float ch_scale = (1.0f - cMB * cK) / sh;
      const float yc = fminf(fmaxf(z, -cTB), cTB);

      // width scan: find bin idx (= largest i in [0,31] with cw[i] <= yc),
      // capture cw[idx], cw[idx+1]
      int idx = 0;
      float cum = 0.0f, cw_k = -cTB, cw_k1 = cTB;
      bool take = true;
      #pragma unroll
      for (int i = 1; i <= 32; ++i) {
        float cwi;
        if (i < 32) {
          cum += cMB + __expf((pm[i - 1] - mw) * invS) * cw_scale;
          cwi = 2.0f * cTB * cum - cTB;
        } else {
          cwi = cTB;  // cw[K] set exactly to TB in reference
        }
        if (take) { cw_k1 = cwi; take = false; }
        if (i < 32 && yc >= cwi) { idx = i; cw_k = cwi; take = true; }
      }

      // height scan: capture ch[idx], ch[idx+1]
      cum = 0.0f;
      float ch_k = -cTB, ch_k1 = cTB;
      #pragma unroll
      for (int i = 1; i < 32; ++i) {
        cum += cMB + __expf((pm[32 + i - 1] - mh) * invS) * ch_scale;
        const float chi = 2.0f * cTB * cum - cTB;
        if (i == idx) ch_k = chi;
        if (i == idx + 1) ch_k1 = chi;
      }

      const float w_k = cw_k1 - cw_k;
      const float h_k = ch_k1 - ch_k;
      // derivatives: d[0]=d[K]=1.0 exactly (pad const); interior from p[2K:] (UNscaled)
      const float d_k  = (idx == 0)  ? 1.0f : cMD + softplusf_(pm[64 + idx - 1]);
      const float d_k1 = (idx == 31) ? 1.0f : cMD + softplusf_(pm[64 + idx]);

      const float s_k  = h_k / w_k;
      const float th   = (yc - cw_k) / w_k;
      const float th1m = th * (1.0f - th);
      const float numv = h_k * (s_k * th * th + d_k * th1m);
      const float denv = s_k + (d_k + d_k1 - 2.0f * s_k) * th1m;
      const float outv = ch_k + numv / denv;
      const float omt  = 1.0f - th;
      const float dnum = s_k * s_k * (d_k1 * th * th + 2.0f * s_k * th1m + d_k * omt * omt);
      const float ladv = __logf(dnum) - 2.0f * __logf(denv);
      const bool inside = (z >= -cTB) && (z <= cTB);
      if (inside) { z = outv; lad += ladv; }
    }
    // no barrier needed here: next writer of sT/sP (t1 of next layer) is
    // behind the ctx-phase barrier, which wave0 reaches only after the spline.
  }

  if (tid < M) {
    gout[m0 + tid] = -0.5f * z * z - 0.9189385332046727f + lad;
  }
}

extern "C" void kernel_launch(void* const* d_in, const int* in_sizes, int n_in,
                              void* d_out, int out_size, void* d_ws, size_t ws_size,
                              hipStream_t stream) {
  const float* gy   = (const float*)d_in[0];
  const float* gctx = (const float*)d_in[1];
  const float* eW1  = (const float*)d_in[2];
  const float* eb1  = (const float*)d_in[3];
  const float* eW2  = (const float*)d_in[4];
  const float* eb2  = (const float*)d_in[5];
  const float* eW3  = (const float*)d_in[6];
  const float* eb3  = (const float*)d_in[7];
  const float* gib  = (const float*)d_in[8];
  const float* gcW  = (const float*)d_in[9];
  const float* gcb  = (const float*)d_in[10];
  const float* bW1  = (const float*)d_in[11];
  const float* bb1  = (const float*)d_in[12];
  const float* bW2  = (const float*)d_in[13];
  const float* bb2  = (const float*)d_in[14];
  const float* bWc  = (const float*)d_in[15];
  const float* bbc  = (const float*)d_in[16];
  const float* goW  = (const float*)d_in[17];
  const float* gob  = (const float*)d_in[18];

  dim3 grid(cB / M);
  dim3 block(NTHREADS);
  nsf_fused<<<grid, block, 0, stream>>>(gy, gctx, eW1, eb1, eW2, eb2, eW3, eb3,
                                        gib, gcW, gcb, bW1, bb1, bW2, bb2,
                                        bWc, bbc, goW, gob, (float*)d_out);
}

// Round 3
// 1166.476 us; speedup vs baseline: 5.5801x; 5.5801x over previous
//
#include <hip/hip_runtime.h>
#include <math.h>

typedef _Float16 hfrag  __attribute__((ext_vector_type(8)));  // 8 f16 = 4 VGPR (MFMA A/B)
typedef _Float16 hpack  __attribute__((ext_vector_type(4)));  // 4 f16 = 8B packed store
typedef float    accf   __attribute__((ext_vector_type(16))); // MFMA C/D

constexpr float cTB = 6.0f;
constexpr float cMB = 0.001f;
constexpr float cMD = 0.001f;

constexpr int SH = 136;   // act buffer stride (halves): 16B-aligned rows, bank-balanced b128
constexpr int SE = 72;    // emb buffer stride (halves)
constexpr int SP = 100;   // p buffer stride (halves): 2-way banks (free)

__device__ __forceinline__ float eluf(float x)  { return x > 0.f ? x : __expf(x) - 1.f; }
__device__ __forceinline__ float sigmf(float x) { return 1.f / (1.f + __expf(-x)); }
__device__ __forceinline__ float softplusf_(float x) { return x > 20.f ? x : log1pf(__expf(x)); }

// ---------------- weight prep: fp32 [n][K][F] -> f16 [n][Fpad][K] ----------------
__global__ void prep_transpose(const float* __restrict__ src, _Float16* __restrict__ dst,
                               int K, int F, int Fpad, int total) {
  int idx = blockIdx.x * 256 + threadIdx.x;
  if (idx >= total) return;
  int k = idx % K;
  int f = (idx / K) % Fpad;
  int n = idx / (K * Fpad);
  float v = (f < F) ? src[(size_t)n * K * F + (size_t)k * F + f] : 0.f;
  dst[idx] = (_Float16)v;
}

// GEMM: D[f][m] += W^T[f][k] * Act^T[k][m].  A-frag row = f0+col (global f16, [f][K]),
// B-frag col = m (LDS [m][k]).  Two n-tiles (m 0-31, 32-63).
#define GEMM2(WROW, BPTR, BSTRIDE, KDIM, A0, A1)                               \
  _Pragma("unroll")                                                            \
  for (int c = 0; c < (KDIM); c += 16) {                                       \
    hfrag av = *(const hfrag*)((WROW) + c + q8);                               \
    hfrag b0 = *(const hfrag*)((BPTR) + col * (BSTRIDE) + c + q8);             \
    hfrag b1 = *(const hfrag*)((BPTR) + (32 + col) * (BSTRIDE) + c + q8);      \
    A0 = __builtin_amdgcn_mfma_f32_32x32x16_f16(av, b0, A0, 0, 0, 0);          \
    A1 = __builtin_amdgcn_mfma_f32_32x32x16_f16(av, b1, A1, 0, 0, 0);          \
  }

__global__ __launch_bounds__(256, 3) void nsf_mfma(
    const float* __restrict__ gy,   const float* __restrict__ gctx,
    const float* __restrict__ eW1,  const float* __restrict__ eb1,
    const float* __restrict__ eb2,  const float* __restrict__ eb3,
    const float* __restrict__ gib,  const float* __restrict__ gcb,
    const float* __restrict__ bb1,  const float* __restrict__ bb2,
    const float* __restrict__ bbc,  const float* __restrict__ gob,
    const _Float16* __restrict__ wE2T, const _Float16* __restrict__ wE3T,
    const _Float16* __restrict__ wCtxT, const _Float16* __restrict__ wW1T,
    const _Float16* __restrict__ wW2T,  const _Float16* __restrict__ wWcT,
    const _Float16* __restrict__ wOutT, float* __restrict__ gout)
{
  __shared__ _Float16 sH[64 * SH];   // act buffer (elu(h) / raw h), [m][k]
  __shared__ _Float16 sT[64 * SH];   // act buffer (elu(t1)); aliased as p-buffer [m][SP]
  __shared__ _Float16 sE[64 * SE];   // embedding [m][k]

  const int tid  = threadIdx.x;
  const int wid  = tid >> 6;      // wave 0..3 -> f-slice
  const int lane = tid & 63;
  const int col  = lane & 31;     // MFMA col (= m_local) / A row offset
  const int q    = lane >> 5;     // k-half selector
  const int q8   = q * 8;
  const int q4   = q * 4;
  const int f0   = wid * 32;
  const int m0   = blockIdx.x * 64;

  // ---------------- embedding ----------------
  {  // stage 1: fp32, 4 e-groups x 64 m
    const int m  = tid & 63;
    const int eg = tid >> 6;
    const float2 c2 = *(const float2*)&gctx[(size_t)(m0 + m) * 2];
    #pragma unroll
    for (int j = 0; j < 16; ++j) {
      const int e = eg * 16 + j;
      sH[m * SE + e] = (_Float16)eluf(c2.x * eW1[e] + c2.y * eW1[64 + e] + eb1[e]);
    }
  }
  __syncthreads();
  {  // stage 2: MFMA, each wave one (ft, nt) tile
    const int ft = wid & 1, nt = wid >> 1;
    accf a = {};
    const _Float16* wr = wE2T + (32 * ft + col) * 64;
    #pragma unroll
    for (int c = 0; c < 64; c += 16) {
      hfrag av = *(const hfrag*)(wr + c + q8);
      hfrag bv = *(const hfrag*)(&sH[(nt * 32 + col) * SE + c + q8]);
      a = __builtin_amdgcn_mfma_f32_32x32x16_f16(av, bv, a, 0, 0, 0);
    }
    const int mrow = nt * 32 + col;
    #pragma unroll
    for (int g = 0; g < 4; ++g) {
      const int e = 32 * ft + 8 * g + q4;
      const float4 b = *(const float4*)&eb2[e];
      hpack pk;
      #pragma unroll
      for (int r = 0; r < 4; ++r) pk[r] = (_Float16)eluf(a[4 * g + r] + (&b.x)[r]);
      *(hpack*)&sT[mrow * SE + e] = pk;
    }
  }
  __syncthreads();
  {  // stage 3: MFMA -> sE
    const int ft = wid & 1, nt = wid >> 1;
    accf a = {};
    const _Float16* wr = wE3T + (32 * ft + col) * 64;
    #pragma unroll
    for (int c = 0; c < 64; c += 16) {
      hfrag av = *(const hfrag*)(wr + c + q8);
      hfrag bv = *(const hfrag*)(&sT[(nt * 32 + col) * SE + c + q8]);
      a = __builtin_amdgcn_mfma_f32_32x32x16_f16(av, bv, a, 0, 0, 0);
    }
    const int mrow = nt * 32 + col;
    #pragma unroll
    for (int g = 0; g < 4; ++g) {
      const int e = 32 * ft + 8 * g + q4;
      const float4 b = *(const float4*)&eb3[e];
      hpack pk;
      #pragma unroll
      for (int r = 0; r < 4; ++r) pk[r] = (_Float16)eluf(a[4 * g + r] + (&b.x)[r]);
      *(hpack*)&sE[mrow * SE + e] = pk;
    }
  }
  __syncthreads();

  // ---------------- flow layers ----------------
  float z = 0.f, lad = 0.f;
  if (tid < 64) z = gy[m0 + tid];

  accf h0, h1;  // raw h (fp32) for this wave's f-slice, n-tiles 0/1

  for (int l = 0; l < 6; ++l) {
    // ---- ctx: h = init_b + ctx_b + emb @ ctx_W ----
    {
      accf a0 = {}, a1 = {};
      const _Float16* wr = wCtxT + (size_t)l * 8192 + (f0 + col) * 64;
      GEMM2(wr, sE, SE, 64, a0, a1)
      #pragma unroll
      for (int nt = 0; nt < 2; ++nt) {
        accf& A = nt ? a1 : a0;
        accf& H = nt ? h1 : h0;
        const int mrow = nt * 32 + col;
        #pragma unroll
        for (int g = 0; g < 4; ++g) {
          const int f = f0 + 8 * g + q4;
          const float4 bi = *(const float4*)&gib[l * 128 + f];
          const float4 bc = *(const float4*)&gcb[l * 128 + f];
          hpack pk;
          #pragma unroll
          for (int r = 0; r < 4; ++r) {
            float hv = A[4 * g + r] + (&bi.x)[r] + (&bc.x)[r];
            H[4 * g + r] = hv;
            pk[r] = (_Float16)eluf(hv);
          }
          *(hpack*)&sH[mrow * SH + f] = pk;
        }
      }
    }
    __syncthreads();

    // ---- residual blocks ----
    for (int jb = 0; jb < 2; ++jb) {
      const int wi = l * 2 + jb;
      {  // t1 = elu(elu(h) @ W1 + b1) -> sT
        accf a0 = {}, a1 = {};
        const _Float16* wr = wW1T + (size_t)wi * 16384 + (f0 + col) * 128;
        GEMM2(wr, sH, SH, 128, a0, a1)
        #pragma unroll
        for (int nt = 0; nt < 2; ++nt) {
          accf& A = nt ? a1 : a0;
          const int mrow = nt * 32 + col;
          #pragma unroll
          for (int g = 0; g < 4; ++g) {
            const int f = f0 + 8 * g + q4;
            const float4 bv = *(const float4*)&bb1[wi * 128 + f];
            hpack pk;
            #pragma unroll
            for (int r = 0; r < 4; ++r) pk[r] = (_Float16)eluf(A[4 * g + r] + (&bv.x)[r]);
            *(hpack*)&sT[mrow * SH + f] = pk;
          }
        }
      }
      __syncthreads();
      {  // t2 = elu(t1)@W2 + b2 ; gate = sigmoid(emb@Wc + bc); h += t2*gate
        accf a0 = {}, a1 = {}, g0 = {}, g1 = {};
        const _Float16* wr2 = wW2T + (size_t)wi * 16384 + (f0 + col) * 128;
        GEMM2(wr2, sT, SH, 128, a0, a1)
        const _Float16* wrc = wWcT + (size_t)wi * 8192 + (f0 + col) * 64;
        GEMM2(wrc, sE, SE, 64, g0, g1)
        const bool last = (jb == 1);
        #pragma unroll
        for (int nt = 0; nt < 2; ++nt) {
          accf& A2 = nt ? a1 : a0;
          accf& AG = nt ? g1 : g0;
          accf& H  = nt ? h1 : h0;
          const int mrow = nt * 32 + col;
          #pragma unroll
          for (int g = 0; g < 4; ++g) {
            const int f = f0 + 8 * g + q4;
            const float4 b2v = *(const float4*)&bb2[wi * 128 + f];
            const float4 bcv = *(const float4*)&bbc[wi * 128 + f];
            hpack pk;
            #pragma unroll
            for (int r = 0; r < 4; ++r) {
              const float gate = sigmf(AG[4 * g + r] + (&bcv.x)[r]);
              const float hv = H[4 * g + r] + (A2[4 * g + r] + (&b2v.x)[r]) * gate;
              H[4 * g + r] = hv;
              pk[r] = (_Float16)(last ? hv : eluf(hv));  // last block: stage RAW h
            }
            *(hpack*)&sH[mrow * SH + f] = pk;
          }
        }
      }
      __syncthreads();
    }

    // ---- p = h @ out_W + out_b  (waves 0-2, F=96 incl. 1 zero pad row) ----
    if (wid < 3) {
      accf a0 = {}, a1 = {};
      const _Float16* wr = wOutT + (size_t)l * 12288 + (f0 + col) * 128;
      GEMM2(wr, sH, SH, 128, a0, a1)
      #pragma unroll
      for (int nt = 0; nt < 2; ++nt) {
        accf& A = nt ? a1 : a0;
        const int mrow = nt * 32 + col;
        #pragma unroll
        for (int g = 0; g < 4; ++g) {
          const int f = f0 + 8 * g + q4;
          hpack pk;
          #pragma unroll
          for (int r = 0; r < 4; ++r) {
            const float ob = (f + r < 95) ? gob[l * 95 + f + r] : 0.f;
            pk[r] = (_Float16)(A[4 * g + r] + ob);
          }
          *(hpack*)&sT[mrow * SP + f] = pk;
        }
      }
    }
    __syncthreads();

    // ---- rational-quadratic spline: wave 0, one lane per sample ----
    // (overlaps with waves 1-3 running next layer's ctx-GEMM; t1's sT write
    //  is behind the post-ctx barrier which wave 0 reaches only after this)
    if (tid < 64) {
      const float invS = 0.08838834764831845f;  // 1/sqrt(128)
      const _Float16* pmv = &sT[tid * SP];
      auto pm = [&](int i) -> float { return (float)pmv[i]; };
      float mw = pm(0), mh = pm(32);
      #pragma unroll
      for (int i = 1; i < 32; ++i) {
        mw = fmaxf(mw, pm(i));
        mh = fmaxf(mh, pm(32 + i));
      }
      float sw = 0.f, sh = 0.f;
      #pragma unroll
      for (int i = 0; i < 32; ++i) {
        sw += __expf((pm(i) - mw) * invS);
        sh += __expf((pm(32 + i) - mh) * invS);
      }
      const float cw_scale = (1.0f - cMB * 32.f) / sw;
      const float ch_scale = (1.0f - cMB * 32.f) / sh;
      const float yc = fminf(fmaxf(z, -cTB), cTB);

      int idx = 0;
      float cum = 0.f, cw_k = -cTB, cw_k1 = cTB;
      bool take = true;
      #pragma unroll
      for (int i = 1; i <= 32; ++i) {
        float cwi;
        if (i < 32) {
          cum += cMB + __expf((pm(i - 1) - mw) * invS) * cw_scale;
          cwi = 2.f * cTB * cum - cTB;
        } else {
          cwi = cTB;
        }
        if (take) { cw_k1 = cwi; take = false; }
        if (i < 32 && yc >= cwi) { idx = i; cw_k = cwi; take = true; }
      }

      cum = 0.f;
      float ch_k = -cTB, ch_k1 = cTB;
      #pragma unroll
      for (int i = 1; i < 32; ++i) {
        cum += cMB + __expf((pm(32 + i - 1) - mh) * invS) * ch_scale;
        const float chi = 2.f * cTB * cum - cTB;
        if (i == idx) ch_k = chi;
        if (i == idx + 1) ch_k1 = chi;
      }

      const float w_k = cw_k1 - cw_k;
      const float h_k = ch_k1 - ch_k;
      const float d_k  = (idx == 0)  ? 1.f : cMD + softplusf_(pm(64 + idx - 1));
      const float d_k1 = (idx == 31) ? 1.f : cMD + softplusf_(pm(64 + idx));

      const float s_k  = h_k / w_k;
      const float th   = (yc - cw_k) / w_k;
      const float th1m = th * (1.f - th);
      const float numv = h_k * (s_k * th * th + d_k * th1m);
      const float denv = s_k + (d_k + d_k1 - 2.f * s_k) * th1m;
      const float outv = ch_k + numv / denv;
      const float omt  = 1.f - th;
      const float dnum = s_k * s_k * (d_k1 * th * th + 2.f * s_k * th1m + d_k * omt * omt);
      const float ladv = __logf(dnum) - 2.f * __logf(denv);
      const bool inside = (z >= -cTB) && (z <= cTB);
      if (inside) { z = outv; lad += ladv; }
    }
  }

  if (tid < 64) {
    gout[m0 + tid] = -0.5f * z * z - 0.9189385332046727f + lad;
  }
}

extern "C" void kernel_launch(void* const* d_in, const int* in_sizes, int n_in,
                              void* d_out, int out_size, void* d_ws, size_t ws_size,
                              hipStream_t stream) {
  const float* gy   = (const float*)d_in[0];
  const float* gctx = (const float*)d_in[1];
  const float* eW1  = (const float*)d_in[2];
  const float* eb1  = (const float*)d_in[3];
  const float* eW2  = (const float*)d_in[4];
  const float* eb2  = (const float*)d_in[5];
  const float* eW3  = (const float*)d_in[6];
  const float* eb3  = (const float*)d_in[7];
  const float* gib  = (const float*)d_in[8];
  const float* gcW  = (const float*)d_in[9];
  const float* gcb  = (const float*)d_in[10];
  const float* bW1  = (const float*)d_in[11];
  const float* bb1  = (const float*)d_in[12];
  const float* bW2  = (const float*)d_in[13];
  const float* bb2  = (const float*)d_in[14];
  const float* bWc  = (const float*)d_in[15];
  const float* bbc  = (const float*)d_in[16];
  const float* goW  = (const float*)d_in[17];
  const float* gob  = (const float*)d_in[18];

  _Float16* ws    = (_Float16*)d_ws;
  _Float16* wE2T  = ws;                  // 64*64
  _Float16* wE3T  = wE2T + 4096;         // 64*64
  _Float16* wCtxT = wE3T + 4096;         // 6*128*64
  _Float16* wW1T  = wCtxT + 49152;       // 12*128*128
  _Float16* wW2T  = wW1T + 196608;       // 12*128*128
  _Float16* wWcT  = wW2T + 196608;       // 12*128*64
  _Float16* wOutT = wWcT + 98304;        // 6*96*128

  auto prep = [&](const float* s, _Float16* d, int K, int F, int Fp, int n) {
    int tot = n * Fp * K;
    prep_transpose<<<(tot + 255) / 256, 256, 0, stream>>>(s, d, K, F, Fp, tot);
  };
  prep(eW2, wE2T, 64, 64, 64, 1);
  prep(eW3, wE3T, 64, 64, 64, 1);
  prep(gcW, wCtxT, 64, 128, 128, 6);
  prep(bW1, wW1T, 128, 128, 128, 12);
  prep(bW2, wW2T, 128, 128, 128, 12);
  prep(bWc, wWcT, 64, 128, 128, 12);
  prep(goW, wOutT, 128, 95, 96, 6);

  nsf_mfma<<<dim3(262144 / 64), dim3(256), 0, stream>>>(
      gy, gctx, eW1, eb1, eb2, eb3, gib, gcb, bb1, bb2, bbc, gob,
      wE2T, wE3T, wCtxT, wW1T, wW2T, wWcT, wOutT, (float*)d_out);
}